// Round 1
// baseline (506.325 us; speedup 1.0000x reference)
//
#include <hip/hip_runtime.h>

#define NN 16384
#define FIN 128
#define FH 64
#define FO 32

// ---------------- graph section ----------------

__global__ void k_deg_init(float* __restrict__ deg) {
    int i = blockIdx.x * 256 + threadIdx.x;
    deg[i] = 1.0f;  // self-loop contribution
}

__global__ void k_deg_edges(const int* __restrict__ dst, float* __restrict__ deg, int E) {
    int e = blockIdx.x * 256 + threadIdx.x;
    if (e < E) atomicAdd(&deg[dst[e] & (NN - 1)], 1.0f);
}

__global__ void k_dinv(float* __restrict__ deg) {
    int i = blockIdx.x * 256 + threadIdx.x;
    deg[i] = rsqrtf(deg[i]);  // deg >= 1 always (self-loop)
}

// h0 = x @ W1   [NN,FIN]@[FIN,FH] -> [NN,FH]
__global__ void k_h0(const float* __restrict__ x, const float* __restrict__ W1,
                     float* __restrict__ h0) {
    int row = blockIdx.x * 4 + (threadIdx.x >> 6);
    int col = threadIdx.x & 63;
    const float* xr = x + row * FIN;
    float acc = 0.f;
#pragma unroll 8
    for (int k = 0; k < FIN; ++k)
        acc = fmaf(xr[k], W1[k * FH + col], acc);
    h0[row * FH + col] = acc;
}

// acc1[i,:] = dinv[i]^2 * h0[i,:]   (self-loop term)
__global__ void k_self1(const float* __restrict__ h0, const float* __restrict__ dinv,
                        float* __restrict__ acc1) {
    int idx = blockIdx.x * 256 + threadIdx.x;
    int i = idx >> 6;
    float d = dinv[i];
    acc1[idx] = d * d * h0[idx];
}

// edge scatter: acc1[dst,:] += dinv[s]*dinv[d] * h0[src,:]  (wave per edge, lane=channel)
__global__ void k_prop1(const int* __restrict__ src, const int* __restrict__ dst,
                        const float* __restrict__ dinv, const float* __restrict__ h0,
                        float* __restrict__ acc1, int E) {
    int t = blockIdx.x * 256 + threadIdx.x;
    int e = t >> 6, l = t & 63;
    if (e >= E) return;
    int s = src[e] & (NN - 1), d = dst[e] & (NN - 1);
    float w = dinv[s] * dinv[d];
    atomicAdd(&acc1[d * FH + l], w * h0[s * FH + l]);
}

// h = relu(acc1 + b1)  in place
__global__ void k_relu_bias(float* __restrict__ acc1, const float* __restrict__ b1) {
    int idx = blockIdx.x * 256 + threadIdx.x;
    float v = acc1[idx] + b1[idx & 63];
    acc1[idx] = v > 0.f ? v : 0.f;
}

// tmu = h @ Wmu, tls = h @ Wls   [NN,FH]@[FH,FO]
__global__ void k_t(const float* __restrict__ h, const float* __restrict__ Wmu,
                    const float* __restrict__ Wls, float* __restrict__ tmu,
                    float* __restrict__ tls) {
    int row = blockIdx.x;
    int l = threadIdx.x;            // 64 threads: 0-31 mu, 32-63 ls
    const float* hr = h + row * FH;
    const float* W = (l < 32) ? Wmu : Wls;
    int c = l & 31;
    float acc = 0.f;
#pragma unroll 8
    for (int k = 0; k < FH; ++k)
        acc = fmaf(hr[k], W[k * FO + c], acc);
    if (l < 32) tmu[row * FO + c] = acc;
    else        tls[row * FO + c] = acc;
}

__global__ void k_self2(const float* __restrict__ tmu, const float* __restrict__ tls,
                        const float* __restrict__ dinv,
                        float* __restrict__ amu, float* __restrict__ als) {
    int idx = blockIdx.x * 256 + threadIdx.x;   // NN*FO total
    int i = idx >> 5;
    float d = dinv[i];
    float w = d * d;
    amu[idx] = w * tmu[idx];
    als[idx] = w * tls[idx];
}

__global__ void k_prop2(const int* __restrict__ src, const int* __restrict__ dst,
                        const float* __restrict__ dinv,
                        const float* __restrict__ tmu, const float* __restrict__ tls,
                        float* __restrict__ amu, float* __restrict__ als, int E) {
    int t = blockIdx.x * 256 + threadIdx.x;
    int e = t >> 6, l = t & 63;
    if (e >= E) return;
    int s = src[e] & (NN - 1), d = dst[e] & (NN - 1);
    float w = dinv[s] * dinv[d];
    if (l < 32) atomicAdd(&amu[d * FO + l],        w * tmu[s * FO + l]);
    else        atomicAdd(&als[d * FO + (l - 32)], w * tls[s * FO + (l - 32)]);
}

// mu = amu + bmu ; logstd = als + bls ; z = mu + eps*exp(logstd)
__global__ void k_z(const float* __restrict__ amu, const float* __restrict__ als,
                    const float* __restrict__ bmu, const float* __restrict__ bls,
                    const float* __restrict__ eps,
                    float* __restrict__ mu_out, float* __restrict__ ls_out,
                    float* __restrict__ z) {
    int idx = blockIdx.x * 256 + threadIdx.x;   // NN*FO
    int c = idx & 31;
    float m = amu[idx] + bmu[c];
    float s = als[idx] + bls[c];
    mu_out[idx] = m;
    ls_out[idx] = s;
    z[idx] = fmaf(eps[idx], __expf(s), m);
}

// ---------------- decode: adj = sigmoid(z @ z^T) ----------------
// 128x128 tile per 256-thread block; 8x8 register micro-tile per thread.
__global__ __launch_bounds__(256) void k_decode(const float* __restrict__ z,
                                                float* __restrict__ out) {
    __shared__ float zi[FO][132];   // transposed, padded to keep 16B alignment
    __shared__ float zj[FO][132];
    int bi = blockIdx.x & 127, bj = blockIdx.x >> 7;
    int t = threadIdx.x;

#pragma unroll
    for (int p = 0; p < 4; ++p) {
        int idx = p * 1024 + t * 4;     // 4096 floats per tile
        int r = idx >> 5;               // row within tile
        int k = idx & 31;
        float4 vi = *(const float4*)(z + ((size_t)(bi * 128 + r)) * FO + k);
        float4 vj = *(const float4*)(z + ((size_t)(bj * 128 + r)) * FO + k);
        zi[k + 0][r] = vi.x; zi[k + 1][r] = vi.y; zi[k + 2][r] = vi.z; zi[k + 3][r] = vi.w;
        zj[k + 0][r] = vj.x; zj[k + 1][r] = vj.y; zj[k + 2][r] = vj.z; zj[k + 3][r] = vj.w;
    }
    __syncthreads();

    int tx = t & 15, ty = t >> 4;
    float acc[8][8];
#pragma unroll
    for (int i = 0; i < 8; ++i)
#pragma unroll
        for (int j = 0; j < 8; ++j) acc[i][j] = 0.f;

    for (int k = 0; k < FO; ++k) {
        float a[8], b[8];
#pragma unroll
        for (int i = 0; i < 8; ++i) a[i] = zi[k][ty * 8 + i];
#pragma unroll
        for (int j = 0; j < 8; ++j) b[j] = zj[k][tx * 8 + j];
#pragma unroll
        for (int i = 0; i < 8; ++i)
#pragma unroll
            for (int j = 0; j < 8; ++j)
                acc[i][j] = fmaf(a[i], b[j], acc[i][j]);
    }

#pragma unroll
    for (int i = 0; i < 8; ++i) {
        size_t o = ((size_t)(bi * 128 + ty * 8 + i)) * NN + bj * 128 + tx * 8;
#pragma unroll
        for (int j = 0; j < 8; j += 4) {
            float4 v;
            v.x = 1.f / (1.f + __expf(-acc[i][j + 0]));
            v.y = 1.f / (1.f + __expf(-acc[i][j + 1]));
            v.z = 1.f / (1.f + __expf(-acc[i][j + 2]));
            v.w = 1.f / (1.f + __expf(-acc[i][j + 3]));
            *(float4*)(out + o + j) = v;
        }
    }
}

// ---------------- launch ----------------

extern "C" void kernel_launch(void* const* d_in, const int* in_sizes, int n_in,
                              void* d_out, int out_size, void* d_ws, size_t ws_size,
                              hipStream_t stream) {
    const float* x    = (const float*)d_in[0];
    const int*   ei   = (const int*)d_in[1];
    const float* W1   = (const float*)d_in[2];
    const float* b1   = (const float*)d_in[3];
    const float* Wmu  = (const float*)d_in[4];
    const float* bmu  = (const float*)d_in[5];
    const float* Wls  = (const float*)d_in[6];
    const float* bls  = (const float*)d_in[7];
    const float* eps  = (const float*)d_in[8];

    int E = in_sizes[1] / 2;
    const int* src = ei;
    const int* dst = ei + E;

    float* ws = (float*)d_ws;
    float* deg  = ws;                       // NN            (becomes dinv in place)
    float* h0   = deg  + NN;                // NN*FH
    float* acc1 = h0   + (size_t)NN * FH;   // NN*FH  (becomes h in place)
    float* tmu  = acc1 + (size_t)NN * FH;   // NN*FO
    float* tls  = tmu  + (size_t)NN * FO;   // NN*FO
    float* amu  = tls  + (size_t)NN * FO;   // NN*FO
    float* als  = amu  + (size_t)NN * FO;   // NN*FO
    float* z    = als  + (size_t)NN * FO;   // NN*FO

    float* adj    = (float*)d_out;
    float* mu_out = adj + (size_t)NN * NN;
    float* ls_out = mu_out + (size_t)NN * FO;

    k_deg_init<<<NN / 256, 256, 0, stream>>>(deg);
    k_deg_edges<<<(E + 255) / 256, 256, 0, stream>>>(dst, deg, E);
    k_dinv<<<NN / 256, 256, 0, stream>>>(deg);
    k_h0<<<NN / 4, 256, 0, stream>>>(x, W1, h0);
    k_self1<<<NN * FH / 256, 256, 0, stream>>>(h0, deg, acc1);
    k_prop1<<<(E * 64 + 255) / 256, 256, 0, stream>>>(src, dst, deg, h0, acc1, E);
    k_relu_bias<<<NN * FH / 256, 256, 0, stream>>>(acc1, b1);
    k_t<<<NN, 64, 0, stream>>>(acc1, Wmu, Wls, tmu, tls);
    k_self2<<<NN * FO / 256, 256, 0, stream>>>(tmu, tls, deg, amu, als);
    k_prop2<<<(E * 64 + 255) / 256, 256, 0, stream>>>(src, dst, deg, tmu, tls, amu, als, E);
    k_z<<<NN * FO / 256, 256, 0, stream>>>(amu, als, bmu, bls, eps, mu_out, ls_out, z);
    k_decode<<<(NN / 128) * (NN / 128), 256, 0, stream>>>(z, adj);
}

// Round 2
// 503.819 us; speedup vs baseline: 1.0050x; 1.0050x over previous
//
#include <hip/hip_runtime.h>

#define NN 16384
#define FIN 128
#define FH 64
#define FO 32

// ---------------- CSR build ----------------

__global__ void k_zero(int* __restrict__ cnt) {
    int i = blockIdx.x * 256 + threadIdx.x;
    cnt[i] = 0;
}

__global__ void k_count(const int* __restrict__ dst, int* __restrict__ cnt, int E) {
    int e = blockIdx.x * 256 + threadIdx.x;
    if (e < E) atomicAdd(&cnt[dst[e] & (NN - 1)], 1);
}

// exclusive scan over NN=16384 counts, single block of 256 threads (64 elems each)
__global__ __launch_bounds__(256) void k_scan(const int* __restrict__ cnt,
                                              int* __restrict__ row) {
    __shared__ int part[256];
    __shared__ int off[257];
    int t = threadIdx.x;
    int base = t * 64;
    int s = 0;
    for (int i = 0; i < 64; ++i) s += cnt[base + i];
    part[t] = s;
    __syncthreads();
    if (t == 0) {
        int a = 0;
        for (int i = 0; i < 256; ++i) { off[i] = a; a += part[i]; }
        off[256] = a;
    }
    __syncthreads();
    int a = off[t];
    for (int i = 0; i < 64; ++i) { row[base + i] = a; a += cnt[base + i]; }
    if (t == 0) row[NN] = off[256];
}

// dinv = rsqrt(cnt+1), zero the fill cursors
__global__ void k_dinv(const int* __restrict__ cnt, float* __restrict__ dinv,
                       int* __restrict__ cur) {
    int i = blockIdx.x * 256 + threadIdx.x;
    dinv[i] = rsqrtf((float)cnt[i] + 1.0f);
    cur[i] = 0;
}

__global__ void k_fill(const int* __restrict__ src, const int* __restrict__ dst,
                       const int* __restrict__ row, int* __restrict__ cur,
                       const float* __restrict__ dinv,
                       int* __restrict__ csr_s, float* __restrict__ csr_w, int E) {
    int e = blockIdx.x * 256 + threadIdx.x;
    if (e >= E) return;
    int s = src[e] & (NN - 1), d = dst[e] & (NN - 1);
    int pos = atomicAdd(&cur[d], 1);
    int slot = row[d] + pos;
    csr_s[slot] = s;
    csr_w[slot] = dinv[s] * dinv[d];
}

// ---------------- dense transforms ----------------

// h0 = x @ W1   [NN,FIN]@[FIN,FH]
__global__ void k_h0(const float* __restrict__ x, const float* __restrict__ W1,
                     float* __restrict__ h0) {
    int row = blockIdx.x * 4 + (threadIdx.x >> 6);
    int col = threadIdx.x & 63;
    const float* xr = x + row * FIN;
    float acc = 0.f;
#pragma unroll 8
    for (int k = 0; k < FIN; ++k)
        acc = fmaf(xr[k], W1[k * FH + col], acc);
    h0[row * FH + col] = acc;
}

// tmu = h @ Wmu, tls = h @ Wls   [NN,FH]@[FH,FO]  (lanes 0-31 mu, 32-63 ls)
__global__ void k_t(const float* __restrict__ h, const float* __restrict__ Wmu,
                    const float* __restrict__ Wls, float* __restrict__ tmu,
                    float* __restrict__ tls) {
    int row = blockIdx.x * 4 + (threadIdx.x >> 6);
    int l = threadIdx.x & 63;
    const float* hr = h + row * FH;
    const float* W = (l < 32) ? Wmu : Wls;
    int c = l & 31;
    float acc = 0.f;
#pragma unroll 8
    for (int k = 0; k < FH; ++k)
        acc = fmaf(hr[k], W[k * FO + c], acc);
    if (l < 32) tmu[row * FO + c] = acc;
    else        tls[row * FO + c] = acc;
}

// ---------------- gather propagates ----------------

// h[i,:] = relu( dinv[i]^2*h0[i,:] + sum_in w*h0[s,:] + b1 )   (wave per node)
__global__ void k_prop1g(const int* __restrict__ row, const int* __restrict__ csr_s,
                         const float* __restrict__ csr_w, const float* __restrict__ dinv,
                         const float* __restrict__ h0, const float* __restrict__ b1,
                         float* __restrict__ h) {
    int t = blockIdx.x * 256 + threadIdx.x;
    int i = t >> 6, l = t & 63;
    int beg = row[i], end = row[i + 1];
    float di = dinv[i];
    float acc = di * di * h0[i * FH + l];
    for (int j = beg; j < end; ++j) {
        int s = csr_s[j];
        float w = csr_w[j];
        acc = fmaf(w, h0[s * FH + l], acc);
    }
    float v = acc + b1[l];
    h[i * FH + l] = v > 0.f ? v : 0.f;
}

// fused layer-2 propagate + reparameterize:
// mu = gather(tmu)+bmu ; ls = gather(tls)+bls ; z = mu + eps*exp(ls)
__global__ void k_prop2g(const int* __restrict__ row, const int* __restrict__ csr_s,
                         const float* __restrict__ csr_w, const float* __restrict__ dinv,
                         const float* __restrict__ tmu, const float* __restrict__ tls,
                         const float* __restrict__ bmu, const float* __restrict__ bls,
                         const float* __restrict__ eps,
                         float* __restrict__ mu_out, float* __restrict__ ls_out,
                         float* __restrict__ z) {
    int t = blockIdx.x * 256 + threadIdx.x;
    int i = t >> 6, l = t & 63;
    int c = l & 31;
    int beg = row[i], end = row[i + 1];
    const float* tp = (l < 32) ? tmu : tls;
    float di = dinv[i];
    float acc = di * di * tp[i * FO + c];
    for (int j = beg; j < end; ++j) {
        int s = csr_s[j];
        float w = csr_w[j];
        acc = fmaf(w, tp[s * FO + c], acc);
    }
    float v = acc + ((l < 32) ? bmu[c] : bls[c]);
    if (l < 32) mu_out[i * FO + c] = v;
    else        ls_out[i * FO + c] = v;
    float other = __shfl_xor(v, 32);   // lane<32 gets ls, lane>=32 gets mu
    if (l < 32)
        z[i * FO + c] = fmaf(eps[i * FO + c], __expf(other), v);
}

// ---------------- decode: adj = sigmoid(z @ z^T) ----------------
__global__ __launch_bounds__(256) void k_decode(const float* __restrict__ z,
                                                float* __restrict__ out) {
    __shared__ float zi[FO][132];
    __shared__ float zj[FO][132];
    int bi = blockIdx.x & 127, bj = blockIdx.x >> 7;
    int t = threadIdx.x;

#pragma unroll
    for (int p = 0; p < 4; ++p) {
        int idx = p * 1024 + t * 4;
        int r = idx >> 5;
        int k = idx & 31;
        float4 vi = *(const float4*)(z + ((size_t)(bi * 128 + r)) * FO + k);
        float4 vj = *(const float4*)(z + ((size_t)(bj * 128 + r)) * FO + k);
        zi[k + 0][r] = vi.x; zi[k + 1][r] = vi.y; zi[k + 2][r] = vi.z; zi[k + 3][r] = vi.w;
        zj[k + 0][r] = vj.x; zj[k + 1][r] = vj.y; zj[k + 2][r] = vj.z; zj[k + 3][r] = vj.w;
    }
    __syncthreads();

    int tx = t & 15, ty = t >> 4;
    float acc[8][8];
#pragma unroll
    for (int i = 0; i < 8; ++i)
#pragma unroll
        for (int j = 0; j < 8; ++j) acc[i][j] = 0.f;

    for (int k = 0; k < FO; ++k) {
        float a[8], b[8];
#pragma unroll
        for (int i = 0; i < 8; ++i) a[i] = zi[k][ty * 8 + i];
#pragma unroll
        for (int j = 0; j < 8; ++j) b[j] = zj[k][tx * 8 + j];
#pragma unroll
        for (int i = 0; i < 8; ++i)
#pragma unroll
            for (int j = 0; j < 8; ++j)
                acc[i][j] = fmaf(a[i], b[j], acc[i][j]);
    }

#pragma unroll
    for (int i = 0; i < 8; ++i) {
        size_t o = ((size_t)(bi * 128 + ty * 8 + i)) * NN + bj * 128 + tx * 8;
#pragma unroll
        for (int j = 0; j < 8; j += 4) {
            float4 v;
            v.x = __builtin_amdgcn_rcpf(1.f + __expf(-acc[i][j + 0]));
            v.y = __builtin_amdgcn_rcpf(1.f + __expf(-acc[i][j + 1]));
            v.z = __builtin_amdgcn_rcpf(1.f + __expf(-acc[i][j + 2]));
            v.w = __builtin_amdgcn_rcpf(1.f + __expf(-acc[i][j + 3]));
            *(float4*)(out + o + j) = v;
        }
    }
}

// ---------------- launch ----------------

extern "C" void kernel_launch(void* const* d_in, const int* in_sizes, int n_in,
                              void* d_out, int out_size, void* d_ws, size_t ws_size,
                              hipStream_t stream) {
    const float* x    = (const float*)d_in[0];
    const int*   ei   = (const int*)d_in[1];
    const float* W1   = (const float*)d_in[2];
    const float* b1   = (const float*)d_in[3];
    const float* Wmu  = (const float*)d_in[4];
    const float* bmu  = (const float*)d_in[5];
    const float* Wls  = (const float*)d_in[6];
    const float* bls  = (const float*)d_in[7];
    const float* eps  = (const float*)d_in[8];

    int E = in_sizes[1] / 2;
    const int* src = ei;
    const int* dst = ei + E;

    float* ws = (float*)d_ws;
    float* dinv  = ws;                        // NN f32
    int*   cnt   = (int*)(dinv + NN);         // NN
    int*   row   = cnt + NN;                  // NN+1
    int*   cur   = row + NN + 1;              // NN
    int*   csr_s = cur + NN;                  // E
    float* csr_w = (float*)(csr_s + E);       // E
    float* h0    = csr_w + E;                 // NN*FH
    float* h     = h0 + (size_t)NN * FH;      // NN*FH
    float* tmu   = h  + (size_t)NN * FH;      // NN*FO
    float* tls   = tmu + (size_t)NN * FO;     // NN*FO
    float* z     = tls + (size_t)NN * FO;     // NN*FO

    float* adj    = (float*)d_out;
    float* mu_out = adj + (size_t)NN * NN;
    float* ls_out = mu_out + (size_t)NN * FO;

    k_zero<<<NN / 256, 256, 0, stream>>>(cnt);
    k_count<<<(E + 255) / 256, 256, 0, stream>>>(dst, cnt, E);
    k_scan<<<1, 256, 0, stream>>>(cnt, row);
    k_dinv<<<NN / 256, 256, 0, stream>>>(cnt, dinv, cur);
    k_fill<<<(E + 255) / 256, 256, 0, stream>>>(src, dst, row, cur, dinv, csr_s, csr_w, E);
    k_h0<<<NN / 4, 256, 0, stream>>>(x, W1, h0);
    k_prop1g<<<NN * FH / 256, 256, 0, stream>>>(row, csr_s, csr_w, dinv, h0, b1, h);
    k_t<<<NN / 4, 256, 0, stream>>>(h, Wmu, Wls, tmu, tls);
    k_prop2g<<<NN * FH / 256, 256, 0, stream>>>(row, csr_s, csr_w, dinv, tmu, tls,
                                                bmu, bls, eps, mu_out, ls_out, z);
    k_decode<<<(NN / 128) * (NN / 128), 256, 0, stream>>>(z, adj);
}

// Round 5
// 408.029 us; speedup vs baseline: 1.2409x; 1.2348x over previous
//
#include <hip/hip_runtime.h>

#define NN 16384
#define FIN 128
#define FH 64
#define FO 32

// ---------------- CSR build ----------------

__global__ void k_zero(int* __restrict__ cnt) {
    int i = blockIdx.x * 256 + threadIdx.x;
    cnt[i] = 0;
}

__global__ void k_count(const int* __restrict__ dst, int* __restrict__ cnt, int E) {
    int e = blockIdx.x * 256 + threadIdx.x;
    if (e < E) atomicAdd(&cnt[dst[e] & (NN - 1)], 1);
}

// exclusive scan over NN=16384 counts, single block of 256 threads (64 elems each)
__global__ __launch_bounds__(256) void k_scan(const int* __restrict__ cnt,
                                              int* __restrict__ row) {
    __shared__ int part[256];
    __shared__ int off[257];
    int t = threadIdx.x;
    int base = t * 64;
    int s = 0;
    for (int i = 0; i < 64; ++i) s += cnt[base + i];
    part[t] = s;
    __syncthreads();
    if (t == 0) {
        int a = 0;
        for (int i = 0; i < 256; ++i) { off[i] = a; a += part[i]; }
        off[256] = a;
    }
    __syncthreads();
    int a = off[t];
    for (int i = 0; i < 64; ++i) { row[base + i] = a; a += cnt[base + i]; }
    if (t == 0) row[NN] = off[256];
}

// dinv = rsqrt(cnt+1), zero the fill cursors
__global__ void k_dinv(const int* __restrict__ cnt, float* __restrict__ dinv,
                       int* __restrict__ cur) {
    int i = blockIdx.x * 256 + threadIdx.x;
    dinv[i] = rsqrtf((float)cnt[i] + 1.0f);
    cur[i] = 0;
}

__global__ void k_fill(const int* __restrict__ src, const int* __restrict__ dst,
                       const int* __restrict__ row, int* __restrict__ cur,
                       const float* __restrict__ dinv,
                       int* __restrict__ csr_s, float* __restrict__ csr_w, int E) {
    int e = blockIdx.x * 256 + threadIdx.x;
    if (e >= E) return;
    int s = src[e] & (NN - 1), d = dst[e] & (NN - 1);
    int pos = atomicAdd(&cur[d], 1);
    int slot = row[d] + pos;
    csr_s[slot] = s;
    csr_w[slot] = dinv[s] * dinv[d];
}

// ---------------- dense transforms ----------------

// h0 = x @ W1   [NN,FIN]@[FIN,FH]
__global__ void k_h0(const float* __restrict__ x, const float* __restrict__ W1,
                     float* __restrict__ h0) {
    int row = blockIdx.x * 4 + (threadIdx.x >> 6);
    int col = threadIdx.x & 63;
    const float* xr = x + row * FIN;
    float acc = 0.f;
#pragma unroll 8
    for (int k = 0; k < FIN; ++k)
        acc = fmaf(xr[k], W1[k * FH + col], acc);
    h0[row * FH + col] = acc;
}

// tmu = h @ Wmu, tls = h @ Wls   [NN,FH]@[FH,FO]  (lanes 0-31 mu, 32-63 ls)
__global__ void k_t(const float* __restrict__ h, const float* __restrict__ Wmu,
                    const float* __restrict__ Wls, float* __restrict__ tmu,
                    float* __restrict__ tls) {
    int row = blockIdx.x * 4 + (threadIdx.x >> 6);
    int l = threadIdx.x & 63;
    const float* hr = h + row * FH;
    const float* W = (l < 32) ? Wmu : Wls;
    int c = l & 31;
    float acc = 0.f;
#pragma unroll 8
    for (int k = 0; k < FH; ++k)
        acc = fmaf(hr[k], W[k * FO + c], acc);
    if (l < 32) tmu[row * FO + c] = acc;
    else        tls[row * FO + c] = acc;
}

// ---------------- gather propagates ----------------

// h[i,:] = relu( dinv[i]^2*h0[i,:] + sum_in w*h0[s,:] + b1 )   (wave per node)
__global__ void k_prop1g(const int* __restrict__ row, const int* __restrict__ csr_s,
                         const float* __restrict__ csr_w, const float* __restrict__ dinv,
                         const float* __restrict__ h0, const float* __restrict__ b1,
                         float* __restrict__ h) {
    int t = blockIdx.x * 256 + threadIdx.x;
    int i = t >> 6, l = t & 63;
    int beg = row[i], end = row[i + 1];
    float di = dinv[i];
    float acc = di * di * h0[i * FH + l];
    for (int j = beg; j < end; ++j) {
        int s = csr_s[j];
        float w = csr_w[j];
        acc = fmaf(w, h0[s * FH + l], acc);
    }
    float v = acc + b1[l];
    h[i * FH + l] = v > 0.f ? v : 0.f;
}

// fused layer-2 propagate + reparameterize:
// mu = gather(tmu)+bmu ; ls = gather(tls)+bls ; z = mu + eps*exp(ls)
__global__ void k_prop2g(const int* __restrict__ row, const int* __restrict__ csr_s,
                         const float* __restrict__ csr_w, const float* __restrict__ dinv,
                         const float* __restrict__ tmu, const float* __restrict__ tls,
                         const float* __restrict__ bmu, const float* __restrict__ bls,
                         const float* __restrict__ eps,
                         float* __restrict__ mu_out, float* __restrict__ ls_out,
                         float* __restrict__ z) {
    int t = blockIdx.x * 256 + threadIdx.x;
    int i = t >> 6, l = t & 63;
    int c = l & 31;
    int beg = row[i], end = row[i + 1];
    const float* tp = (l < 32) ? tmu : tls;
    float di = dinv[i];
    float acc = di * di * tp[i * FO + c];
    for (int j = beg; j < end; ++j) {
        int s = csr_s[j];
        float w = csr_w[j];
        acc = fmaf(w, tp[s * FO + c], acc);
    }
    float v = acc + ((l < 32) ? bmu[c] : bls[c]);
    if (l < 32) mu_out[i * FO + c] = v;
    else        ls_out[i * FO + c] = v;
    float other = __shfl_xor(v, 32);   // lane<32 gets ls, lane>=32 gets mu
    if (l < 32)
        z[i * FO + c] = fmaf(eps[i * FO + c], __expf(other), v);
}

// ---------------- decode: adj = sigmoid(z @ z^T) ----------------
// 128x128 tile per 256-thread block. Thread (tx,ty), tx=t&15, ty=t>>4:
//   rows ty*8 + i (i=0..7)
//   cols cb*64 + tx*4 + j (cb=0,1; j=0..3)  <- interleaved so stores coalesce
__global__ __launch_bounds__(256) void k_decode(const float* __restrict__ z,
                                                float* __restrict__ out) {
    __shared__ float zi[FO][132];
    __shared__ float zj[FO][132];
    int bi = blockIdx.x & 127, bj = blockIdx.x >> 7;
    int t = threadIdx.x;

#pragma unroll
    for (int p = 0; p < 4; ++p) {
        int idx = p * 1024 + t * 4;
        int r = idx >> 5;
        int k = idx & 31;
        float4 vi = *(const float4*)(z + ((size_t)(bi * 128 + r)) * FO + k);
        float4 vj = *(const float4*)(z + ((size_t)(bj * 128 + r)) * FO + k);
        zi[k + 0][r] = vi.x; zi[k + 1][r] = vi.y; zi[k + 2][r] = vi.z; zi[k + 3][r] = vi.w;
        zj[k + 0][r] = vj.x; zj[k + 1][r] = vj.y; zj[k + 2][r] = vj.z; zj[k + 3][r] = vj.w;
    }
    __syncthreads();

    int tx = t & 15, ty = t >> 4;
    float acc[8][8];   // [i][cb*4+j]
#pragma unroll
    for (int i = 0; i < 8; ++i)
#pragma unroll
        for (int j = 0; j < 8; ++j) acc[i][j] = 0.f;

    for (int k = 0; k < FO; ++k) {
        float a[8];
#pragma unroll
        for (int i = 0; i < 8; ++i) a[i] = zi[k][ty * 8 + i];
        float4 b0 = *(const float4*)&zj[k][tx * 4];        // cols tx*4..+3
        float4 b1v = *(const float4*)&zj[k][64 + tx * 4];  // cols 64+tx*4..+3
        float b[8] = {b0.x, b0.y, b0.z, b0.w, b1v.x, b1v.y, b1v.z, b1v.w};
#pragma unroll
        for (int i = 0; i < 8; ++i)
#pragma unroll
            for (int j = 0; j < 8; ++j)
                acc[i][j] = fmaf(a[i], b[j], acc[i][j]);
    }

#pragma unroll
    for (int i = 0; i < 8; ++i) {
        size_t rowoff = ((size_t)(bi * 128 + ty * 8 + i)) * NN + bj * 128;
#pragma unroll
        for (int cb = 0; cb < 2; ++cb) {
            float4 v;
            v.x = __builtin_amdgcn_rcpf(1.f + __expf(-acc[i][cb * 4 + 0]));
            v.y = __builtin_amdgcn_rcpf(1.f + __expf(-acc[i][cb * 4 + 1]));
            v.z = __builtin_amdgcn_rcpf(1.f + __expf(-acc[i][cb * 4 + 2]));
            v.w = __builtin_amdgcn_rcpf(1.f + __expf(-acc[i][cb * 4 + 3]));
            *(float4*)(out + rowoff + cb * 64 + tx * 4) = v;
        }
    }
}

// ---------------- launch ----------------

extern "C" void kernel_launch(void* const* d_in, const int* in_sizes, int n_in,
                              void* d_out, int out_size, void* d_ws, size_t ws_size,
                              hipStream_t stream) {
    const float* x    = (const float*)d_in[0];
    const int*   ei   = (const int*)d_in[1];
    const float* W1   = (const float*)d_in[2];
    const float* b1   = (const float*)d_in[3];
    const float* Wmu  = (const float*)d_in[4];
    const float* bmu  = (const float*)d_in[5];
    const float* Wls  = (const float*)d_in[6];
    const float* bls  = (const float*)d_in[7];
    const float* eps  = (const float*)d_in[8];

    int E = in_sizes[1] / 2;
    const int* src = ei;
    const int* dst = ei + E;

    float* ws = (float*)d_ws;
    float* dinv  = ws;                        // NN f32
    int*   cnt   = (int*)(dinv + NN);         // NN
    int*   row   = cnt + NN;                  // NN+1
    int*   cur   = row + NN + 1;              // NN
    int*   csr_s = cur + NN;                  // E
    float* csr_w = (float*)(csr_s + E);       // E
    float* h0    = csr_w + E;                 // NN*FH
    float* h     = h0 + (size_t)NN * FH;      // NN*FH
    float* tmu   = h  + (size_t)NN * FH;      // NN*FO
    float* tls   = tmu + (size_t)NN * FO;     // NN*FO
    float* z     = tls + (size_t)NN * FO;     // NN*FO

    float* adj    = (float*)d_out;
    float* mu_out = adj + (size_t)NN * NN;
    float* ls_out = mu_out + (size_t)NN * FO;

    k_zero<<<NN / 256, 256, 0, stream>>>(cnt);
    k_count<<<(E + 255) / 256, 256, 0, stream>>>(dst, cnt, E);
    k_scan<<<1, 256, 0, stream>>>(cnt, row);
    k_dinv<<<NN / 256, 256, 0, stream>>>(cnt, dinv, cur);
    k_fill<<<(E + 255) / 256, 256, 0, stream>>>(src, dst, row, cur, dinv, csr_s, csr_w, E);
    k_h0<<<NN / 4, 256, 0, stream>>>(x, W1, h0);
    k_prop1g<<<NN * FH / 256, 256, 0, stream>>>(row, csr_s, csr_w, dinv, h0, b1, h);
    k_t<<<NN / 4, 256, 0, stream>>>(h, Wmu, Wls, tmu, tls);
    k_prop2g<<<NN * FH / 256, 256, 0, stream>>>(row, csr_s, csr_w, dinv, tmu, tls,
                                                bmu, bls, eps, mu_out, ls_out, z);
    k_decode<<<(NN / 128) * (NN / 128), 256, 0, stream>>>(z, adj);
}